// Round 1
// baseline (49.956 us; speedup 1.0000x reference)
//
#include <hip/hip_runtime.h>

// Problem constants (from reference): B=8192, NJ=14, COL=14, sigma=1, radius=4.
#define NJ    14
#define COLS  14
#define TILE  196           // 14*14
#define BLK   256
#define WPB   4             // waves per block (256/64)
#define GRID1 2048
#define TOTW  (GRID1*WPB)   // 8192 waves, grid-stride over B*NJ joints

__device__ __forceinline__ float wave_reduce_add(float x) {
#pragma unroll
  for (int off = 32; off >= 1; off >>= 1) x += __shfl_xor(x, off);
  return x;
}

__global__ __launch_bounds__(BLK) void joint_kernel(
    const float* __restrict__ o, const float* __restrict__ h,
    const float* __restrict__ t, const float* __restrict__ v,
    float* __restrict__ part, int njoint)
{
  // gaussian_filter taps: exp(-0.5*k^2), k=-4..4, normalized (float32)
  static const float W[9] = {
    1.3383063e-04f, 4.4318615e-03f, 5.3991128e-02f, 2.4197145e-01f,
    3.9894347e-01f, 2.4197145e-01f, 5.3991128e-02f, 4.4318615e-03f,
    1.3383063e-04f };

  const int lane = threadIdx.x & 63;
  const int wid  = threadIdx.x >> 6;
  const int wg   = blockIdx.x * WPB + wid;

  float s_acc = 0.0f;   // sum of squared diffs (heatmap + coord)
  float n_acc = 0.0f;   // sum of v entries (N1 = n/2)

  for (int g = wg; g < njoint; g += TOTW) {
    const int b = g / NJ;
    const int j = g - b * NJ;

    // ---- load 14x14 heatmap tile: 49 float4 = 784 contiguous bytes ----
    const float* hb = h + (size_t)g * TILE;
    float4 hv;
    if (lane < 49) hv = ((const float4*)hb)[lane];
    else           hv = make_float4(-3.0e38f, -3.0e38f, -3.0e38f, -3.0e38f);
    const float ha[4] = {hv.x, hv.y, hv.z, hv.w};

    // ---- argmax with first-index tie-break (matches jnp.argmax) ----
    float bm = ha[0]; int bi = 4*lane;
    if (ha[1] > bm) { bm = ha[1]; bi = 4*lane+1; }
    if (ha[2] > bm) { bm = ha[2]; bi = 4*lane+2; }
    if (ha[3] > bm) { bm = ha[3]; bi = 4*lane+3; }
    if (lane >= 49) bi = 0x3fffffff;
#pragma unroll
    for (int off = 32; off >= 1; off >>= 1) {
      const float om = __shfl_xor(bm, off);
      const int   oi = __shfl_xor(bi, off);
      if (om > bm || (om == bm && oi < bi)) { bm = om; bi = oi; }
    }
    const int yC = bi / COLS;
    const int xC = bi - yC * COLS;

    // ---- uniform per-joint scalars ----
    const float t0 = t[2*g+0], t1 = t[2*g+1];
    const float v0 = v[2*g+0], v1 = v[2*g+1];
    const bool vis = ((int)v0) == 1;

    int xi = (int)(t0 * 14.0f); xi = min(max(xi, 0), 13);
    int yi = (int)(t1 * 14.0f); yi = min(max(yi, 0), 13);

    // ---- 1-D blur responses: ry in lanes 0..13, rx in lanes 16..29 ----
    // symmetric ('reflect') padding: q<0 -> -1-q ; q>13 -> 27-q
    const int pos  = lane & 15;
    const int peak = (lane & 16) ? xi : yi;
    float rv = 0.0f;
    if (pos < 14) {
#pragma unroll
      for (int k = 0; k < 9; ++k) {
        const int q = pos + (k - 4);
        const int m = (q < 0) ? (-1 - q) : ((q > 13) ? (27 - q) : q);
        if (m == peak) rv += W[k];
      }
    }
    // per-group (16-lane) max -> normalization denom; tile min is exactly 0
    float mx = rv;
#pragma unroll
    for (int off = 1; off <= 8; off <<= 1)
      mx = fmaxf(mx, __shfl_xor(mx, off, 16));
    const float mxy = __shfl(mx, 0);
    const float mxx = __shfl(mx, 16);
    const float inv = vis ? (1.0f / (mxy * mxx)) : 0.0f;

    // ---- heatmap MSE: diff = h - tt ; row0 zeroed when invisible ----
    float s = 0.0f;
#pragma unroll
    for (int c = 0; c < 4; ++c) {
      const int idx = 4*lane + c;
      const int y = idx / COLS;
      const int x = idx - y * COLS;
      const float ryv = __shfl(rv, y);        // valid lanes: y<=13
      const float rxv = __shfl(rv, 16 + x);   // lanes 16..29
      const float tt  = ryv * rxv * inv;      // 0 when invisible
      float d = ha[c] - tt;
      if (y == 0 && !vis) d = 0.0f;
      if (lane < 49) s += d * d;
    }

    // ---- coordinate loss (lane 0 only; 2 gathered o reads) ----
    if (lane == 0) {
      const size_t ob = ((size_t)b * (2*NJ) + j) * TILE + (size_t)bi;
      const float ox = o[ob];
      const float oy = o[ob + (size_t)NJ * TILE];
      const bool cond = bm > 0.5f;
      const float scale = 1.0f / 14.0f;
      const float px = cond ? (ox + (float)xC) * scale : 0.0f;
      const float py = cond ? (oy + (float)yC) * scale : 0.0f;
      const float d0 = (px - t0) * v0;
      const float d1 = (py - t1) * v1;
      s += d0*d0 + d1*d1;
      n_acc += v0 + v1;
    }
    s_acc += s;
  }

  // ---- deterministic reduction: wave -> block -> per-block partial ----
  s_acc = wave_reduce_add(s_acc);
  n_acc = wave_reduce_add(n_acc);

  __shared__ float rs[WPB], rn[WPB];
  if (lane == 0) { rs[wid] = s_acc; rn[wid] = n_acc; }
  __syncthreads();
  if (threadIdx.x == 0) {
    float S = 0.0f, N = 0.0f;
#pragma unroll
    for (int i = 0; i < WPB; ++i) { S += rs[i]; N += rn[i]; }
    part[blockIdx.x]         = S;
    part[GRID1 + blockIdx.x] = N;
  }
}

__global__ __launch_bounds__(256) void finalize_kernel(
    const float* __restrict__ part, float* __restrict__ out)
{
  float s = 0.0f, n = 0.0f;
  for (int i = threadIdx.x; i < GRID1; i += 256) {
    s += part[i];
    n += part[GRID1 + i];
  }
  s = wave_reduce_add(s);
  n = wave_reduce_add(n);
  __shared__ float rs[4], rn[4];
  const int lane = threadIdx.x & 63, wid = threadIdx.x >> 6;
  if (lane == 0) { rs[wid] = s; rn[wid] = n; }
  __syncthreads();
  if (threadIdx.x == 0) {
    const float S = rs[0] + rs[1] + rs[2] + rs[3];
    const float N = rn[0] + rn[1] + rn[2] + rn[3];
    out[0] = S / (0.5f * N);   // (d1_sum + d2_sum) / N1,  N1 = sum(v)/2
  }
}

extern "C" void kernel_launch(void* const* d_in, const int* in_sizes, int n_in,
                              void* d_out, int out_size, void* d_ws, size_t ws_size,
                              hipStream_t stream)
{
  const float* o = (const float*)d_in[0];  // [B, 2*NJ, 14, 14]
  const float* h = (const float*)d_in[1];  // [B, NJ, 14, 14]
  const float* t = (const float*)d_in[2];  // [B, NJ, 2]
  const float* v = (const float*)d_in[3];  // [B, NJ, 2]
  const int njoint = in_sizes[1] / TILE;   // B*NJ = 114688

  float* part = (float*)d_ws;              // 2*GRID1 floats = 16 KB, fully rewritten each call
  joint_kernel<<<GRID1, BLK, 0, stream>>>(o, h, t, v, part, njoint);
  finalize_kernel<<<1, 256, 0, stream>>>(part, (float*)d_out);
}

// Round 2
// 37.462 us; speedup vs baseline: 1.3335x; 1.3335x over previous
//
#include <hip/hip_runtime.h>

// Problem constants: B=8192, NJ=14, COL=14, sigma=1, radius=4.
#define NJ    14
#define TILE  196          // 14*14
#define BLK   256

// exp(-0.5*d*d) with the 9-tap cutoff (|d|<=4), via v_exp_f32.
__device__ __forceinline__ float gtap(int d) {
  const int d2 = d * d;
  const float e = exp2f(-0.72134752044448169f * (float)d2);  // 0.5*log2(e)
  return (d2 <= 16) ? e : 0.0f;
}

// 1-D blurred-impulse response at position p (compile-time) for peak pk,
// including scipy 'reflect' (symmetric) padding terms. Unnormalized: the
// kernel-sum normalization cancels in tt = g/max(g).
__device__ __forceinline__ float uresp(int p, int pk) {
  float s = gtap(p - pk);
  if (p <= 3)  s += gtap(p + pk + 1);   // low reflection  (q<0 -> -1-q)
  if (p >= 10) s += gtap(27 - p - pk);  // high reflection (q>13 -> 27-q)
  return s;
}

__device__ __forceinline__ float wave_sum(float x) {
#pragma unroll
  for (int off = 32; off >= 1; off >>= 1) x += __shfl_xor(x, off);
  return x;
}

__global__ __launch_bounds__(BLK) void joint_kernel(
    const float* __restrict__ o, const float* __restrict__ h,
    const float* __restrict__ t, const float* __restrict__ v,
    float* __restrict__ part, int njoint, int nblocks)
{
  const int g = blockIdx.x * BLK + threadIdx.x;

  float s_acc = 0.0f, n_acc = 0.0f;

  if (g < njoint) {
    const int b = g / NJ;
    const int j = g - b * NJ;

    const float2 tv = ((const float2*)t)[g];
    const float2 vv = ((const float2*)v)[g];
    const bool vis = ((int)vv.x) == 1;

    int xi = (int)(tv.x * 14.0f); xi = min(max(xi, 0), 13);
    int yi = (int)(tv.y * 14.0f); yi = min(max(yi, 0), 13);

    // ---- analytic 1-D responses (registers, compile-time indexed) ----
    float uy[14], ux[14];
    float Sy2 = 0.0f, Sx2 = 0.0f;
#pragma unroll
    for (int p = 0; p < 14; ++p) {
      const float a = uresp(p, yi);
      const float c = uresp(p, xi);
      uy[p] = a; ux[p] = c;
      Sy2 = fmaf(a, a, Sy2);
      Sx2 = fmaf(c, c, Sx2);
    }
    // max of g is at the peak (reflection terms < center tap elsewhere)
    const float maxy = 1.0f + gtap(2 * yi + 1) + gtap(27 - 2 * yi);
    const float maxx = 1.0f + gtap(2 * xi + 1) + gtap(27 - 2 * xi);
    const float inv = vis ? (1.0f / (maxy * maxx)) : 0.0f;

    // ---- single streaming pass over the 14x14 tile ----
    const float4* hp = (const float4*)(h + (size_t)g * TILE);
    float bm = -3.0e38f; int bi = 0;
    float sh2 = 0.0f, cross = 0.0f, q0 = 0.0f, rowdot = 0.0f;
#pragma unroll
    for (int f = 0; f < 49; ++f) {
      const float4 q = hp[f];
      const float qa[4] = {q.x, q.y, q.z, q.w};
#pragma unroll
      for (int c = 0; c < 4; ++c) {
        const int idx = 4 * f + c;
        const int y = idx / 14;
        const int x = idx - 14 * y;          // compile-time
        const float hv = qa[c];
        if (hv > bm) { bm = hv; bi = idx; }  // first-index tie-break
        const float h2 = hv * hv;
        sh2 += h2;
        if (y == 0) q0 += h2;
        rowdot = fmaf(hv, ux[x], rowdot);
        if (x == 13) { cross = fmaf(uy[y], rowdot, cross); rowdot = 0.0f; }
      }
    }

    // ---- heatmap loss: sum(h-tt)^2 = sh2 - 2*inv*cross + inv^2*Sy2*Sx2 ----
    float s = sh2 - 2.0f * inv * cross + inv * inv * Sy2 * Sx2;
    if (!vis) s -= q0;   // row0 of diff zeroed for invisible joints

    // ---- coordinate loss (argmax-dependent gather) ----
    const int yC = bi / 14;
    const int xC = bi - 14 * yC;
    const size_t ob = ((size_t)b * (2 * NJ) + j) * TILE + (size_t)bi;
    const float ox = o[ob];
    const float oy = o[ob + (size_t)NJ * TILE];
    const bool cond = bm > 0.5f;
    const float sc = 1.0f / 14.0f;
    const float px = cond ? (ox + (float)xC) * sc : 0.0f;
    const float py = cond ? (oy + (float)yC) * sc : 0.0f;
    const float d0 = (px - tv.x) * vv.x;
    const float d1 = (py - tv.y) * vv.y;
    s += d0 * d0 + d1 * d1;

    s_acc = s;
    n_acc = vv.x + vv.y;
  }

  // ---- deterministic block reduction ----
  s_acc = wave_sum(s_acc);
  n_acc = wave_sum(n_acc);
  __shared__ float rs[4], rn[4];
  const int lane = threadIdx.x & 63, wid = threadIdx.x >> 6;
  if (lane == 0) { rs[wid] = s_acc; rn[wid] = n_acc; }
  __syncthreads();
  if (threadIdx.x == 0) {
    part[blockIdx.x]           = rs[0] + rs[1] + rs[2] + rs[3];
    part[nblocks + blockIdx.x] = rn[0] + rn[1] + rn[2] + rn[3];
  }
}

__global__ __launch_bounds__(BLK) void finalize_kernel(
    const float* __restrict__ part, float* __restrict__ out, int nblocks)
{
  float s = 0.0f, n = 0.0f;
  for (int i = threadIdx.x; i < nblocks; i += BLK) {
    s += part[i];
    n += part[nblocks + i];
  }
  s = wave_sum(s);
  n = wave_sum(n);
  __shared__ float rs[4], rn[4];
  const int lane = threadIdx.x & 63, wid = threadIdx.x >> 6;
  if (lane == 0) { rs[wid] = s; rn[wid] = n; }
  __syncthreads();
  if (threadIdx.x == 0) {
    const float S = rs[0] + rs[1] + rs[2] + rs[3];
    const float N = rn[0] + rn[1] + rn[2] + rn[3];
    out[0] = S / (0.5f * N);   // (d1_sum + d2_sum) / N1, N1 = sum(v)/2
  }
}

extern "C" void kernel_launch(void* const* d_in, const int* in_sizes, int n_in,
                              void* d_out, int out_size, void* d_ws, size_t ws_size,
                              hipStream_t stream)
{
  const float* o = (const float*)d_in[0];  // [B, 2*NJ, 14, 14]
  const float* h = (const float*)d_in[1];  // [B, NJ, 14, 14]
  const float* t = (const float*)d_in[2];  // [B, NJ, 2]
  const float* v = (const float*)d_in[3];  // [B, NJ, 2]
  const int njoint = in_sizes[1] / TILE;   // B*NJ = 114688
  const int nblocks = (njoint + BLK - 1) / BLK;  // 448

  float* part = (float*)d_ws;  // 2*nblocks floats, fully rewritten each call
  joint_kernel<<<nblocks, BLK, 0, stream>>>(o, h, t, v, part, njoint, nblocks);
  finalize_kernel<<<1, BLK, 0, stream>>>(part, (float*)d_out, nblocks);
}

// Round 3
// 34.594 us; speedup vs baseline: 1.4440x; 1.0829x over previous
//
#include <hip/hip_runtime.h>

// Problem constants: B=8192, NJ=14, COL=14, sigma=1, radius=4.
#define NJ    14
#define TILE  196          // 14*14
#define BLK   256
#define JPB   64           // joints per block (one per lane; 4 waves split the tile)

// exp(-0.5*d*d) with the 9-tap cutoff (|d|<=4), via v_exp_f32.
__device__ __forceinline__ float gtap(int d) {
  const int d2 = d * d;
  const float e = exp2f(-0.72134752044448169f * (float)d2);  // 0.5*log2(e)
  return (d2 <= 16) ? e : 0.0f;
}

// 1-D blurred-impulse response at position p for peak pk, with scipy
// 'reflect' padding folded in. Unnormalized (kernel-sum cancels in g/max).
__device__ __forceinline__ float uresp(int p, int pk) {
  float s = gtap(p - pk);
  if (p <= 3)  s += gtap(p + pk + 1);   // low reflection  (q<0 -> -1-q)
  if (p >= 10) s += gtap(27 - p - pk);  // high reflection (q>13 -> 27-q)
  return s;
}

__device__ __forceinline__ float wave_sum(float x) {
#pragma unroll
  for (int off = 32; off >= 1; off >>= 1) x += __shfl_xor(x, off);
  return x;
}

// Wave K processes float4 indices f = 4i + K of its lane's tile.
// All tile indices are compile-time -> uy/ux stay in registers.
template<int K>
__device__ __forceinline__ void accum_part(const float4* __restrict__ hp,
    const float (&uy)[14], const float (&ux)[14],
    float& bm, int& bi, float& sh2, float& cross, float& q0)
{
  const int NI = (K == 0) ? 13 : 12;   // 49 float4 = 13+12+12+12
#pragma unroll
  for (int i = 0; i < NI; ++i) {
    const int f = 4 * i + K;
    const float4 q = hp[f];
    const float qa[4] = {q.x, q.y, q.z, q.w};
#pragma unroll
    for (int c = 0; c < 4; ++c) {
      const int idx = 4 * f + c;
      const int y = idx / 14;
      const int x = idx - 14 * y;            // compile-time
      const float hv = qa[c];
      if (hv > bm) { bm = hv; bi = idx; }    // first-index within part
      sh2 = fmaf(hv, hv, sh2);
      if (y == 0) q0 = fmaf(hv, hv, q0);     // row-0 energy (invis fixup)
      cross = fmaf(hv, uy[y] * ux[x], cross);
    }
  }
}

__global__ __launch_bounds__(BLK, 4) void joint_kernel(
    const float* __restrict__ o, const float* __restrict__ h,
    const float* __restrict__ t, const float* __restrict__ v,
    float* __restrict__ part, int njoint, int nblocks)
{
  __shared__ float sm_bm[4][JPB];
  __shared__ int   sm_bi[4][JPB];
  __shared__ float sm_s2[4][JPB];
  __shared__ float sm_cr[4][JPB];
  __shared__ float sm_q0[4][JPB];

  const int lane = threadIdx.x & 63;
  const int wid  = threadIdx.x >> 6;
  const int jg   = blockIdx.x * JPB + lane;
  const bool valid = jg < njoint;

  float uy[14], ux[14];
  float bm = -3.0e38f; int bi = 0;
  float sh2 = 0.0f, cross = 0.0f, q0 = 0.0f;
  float2 tv = make_float2(0.0f, 0.0f);
  int xi = 0, yi = 0;

  if (valid) {
    tv = ((const float2*)t)[jg];
    xi = min(max((int)(tv.x * 14.0f), 0), 13);
    yi = min(max((int)(tv.y * 14.0f), 0), 13);
#pragma unroll
    for (int p = 0; p < 14; ++p) { uy[p] = uresp(p, yi); ux[p] = uresp(p, xi); }

    const float4* hp = (const float4*)(h + (size_t)jg * TILE);
    switch (wid) {   // wave-uniform branch: no lane divergence
      case 0: accum_part<0>(hp, uy, ux, bm, bi, sh2, cross, q0); break;
      case 1: accum_part<1>(hp, uy, ux, bm, bi, sh2, cross, q0); break;
      case 2: accum_part<2>(hp, uy, ux, bm, bi, sh2, cross, q0); break;
      default: accum_part<3>(hp, uy, ux, bm, bi, sh2, cross, q0); break;
    }
  }

  sm_bm[wid][lane] = bm;  sm_bi[wid][lane] = bi;
  sm_s2[wid][lane] = sh2; sm_cr[wid][lane] = cross; sm_q0[wid][lane] = q0;
  __syncthreads();

  float s_acc = 0.0f, n_acc = 0.0f;
  if (wid == 0) {
    // ---- combine the 4 parts for this lane's joint ----
    float Bm = sm_bm[0][lane]; int Bi = sm_bi[0][lane];
    float S2 = sm_s2[0][lane], Cr = sm_cr[0][lane], Q0 = sm_q0[0][lane];
#pragma unroll
    for (int w = 1; w < 4; ++w) {
      const float m = sm_bm[w][lane]; const int i = sm_bi[w][lane];
      if (m > Bm || (m == Bm && i < Bi)) { Bm = m; Bi = i; }  // global first-index
      S2 += sm_s2[w][lane]; Cr += sm_cr[w][lane]; Q0 += sm_q0[w][lane];
    }

    if (valid) {
      const float2 vv = ((const float2*)v)[jg];
      const bool vis = ((int)vv.x) == 1;

      float Sy2 = 0.0f, Sx2 = 0.0f;
#pragma unroll
      for (int p = 0; p < 14; ++p) {
        Sy2 = fmaf(uy[p], uy[p], Sy2);
        Sx2 = fmaf(ux[p], ux[p], Sx2);
      }
      const float maxy = 1.0f + gtap(2 * yi + 1) + gtap(27 - 2 * yi);
      const float maxx = 1.0f + gtap(2 * xi + 1) + gtap(27 - 2 * xi);
      const float inv = vis ? (1.0f / (maxy * maxx)) : 0.0f;

      // sum(h-tt)^2 = S2 - 2*inv*Cr + inv^2*Sy2*Sx2 ; row0 zeroed if invis
      float s = S2 - 2.0f * inv * Cr + inv * inv * Sy2 * Sx2;
      if (!vis) s -= Q0;

      // ---- coordinate loss (argmax-dependent gather) ----
      const int b = jg / NJ;
      const int j = jg - b * NJ;
      const int yC = Bi / 14;
      const int xC = Bi - 14 * yC;
      const size_t ob = ((size_t)b * (2 * NJ) + j) * TILE + (size_t)Bi;
      const float ox = o[ob];
      const float oy = o[ob + (size_t)NJ * TILE];
      const bool cond = Bm > 0.5f;
      const float sc = 1.0f / 14.0f;
      const float px = cond ? (ox + (float)xC) * sc : 0.0f;
      const float py = cond ? (oy + (float)yC) * sc : 0.0f;
      const float d0 = (px - tv.x) * vv.x;
      const float d1 = (py - tv.y) * vv.y;
      s += d0 * d0 + d1 * d1;

      s_acc = s;
      n_acc = vv.x + vv.y;
    }

    // ---- deterministic wave-0 reduction -> per-block partial ----
    s_acc = wave_sum(s_acc);
    n_acc = wave_sum(n_acc);
    if (lane == 0) {
      part[blockIdx.x]           = s_acc;
      part[nblocks + blockIdx.x] = n_acc;
    }
  }
}

__global__ __launch_bounds__(BLK) void finalize_kernel(
    const float* __restrict__ part, float* __restrict__ out, int nblocks)
{
  float s = 0.0f, n = 0.0f;
  for (int i = threadIdx.x; i < nblocks; i += BLK) {
    s += part[i];
    n += part[nblocks + i];
  }
  s = wave_sum(s);
  n = wave_sum(n);
  __shared__ float rs[4], rn[4];
  const int lane = threadIdx.x & 63, wid = threadIdx.x >> 6;
  if (lane == 0) { rs[wid] = s; rn[wid] = n; }
  __syncthreads();
  if (threadIdx.x == 0) {
    const float S = rs[0] + rs[1] + rs[2] + rs[3];
    const float N = rn[0] + rn[1] + rn[2] + rn[3];
    out[0] = S / (0.5f * N);   // (d1_sum + d2_sum) / N1, N1 = sum(v)/2
  }
}

extern "C" void kernel_launch(void* const* d_in, const int* in_sizes, int n_in,
                              void* d_out, int out_size, void* d_ws, size_t ws_size,
                              hipStream_t stream)
{
  const float* o = (const float*)d_in[0];  // [B, 2*NJ, 14, 14]
  const float* h = (const float*)d_in[1];  // [B, NJ, 14, 14]
  const float* t = (const float*)d_in[2];  // [B, NJ, 2]
  const float* v = (const float*)d_in[3];  // [B, NJ, 2]
  const int njoint = in_sizes[1] / TILE;          // B*NJ = 114688
  const int nblocks = (njoint + JPB - 1) / JPB;   // 1792 -> 7 blocks/CU exactly

  float* part = (float*)d_ws;  // 2*nblocks floats, fully rewritten each call
  joint_kernel<<<nblocks, BLK, 0, stream>>>(o, h, t, v, part, njoint, nblocks);
  finalize_kernel<<<1, BLK, 0, stream>>>(part, (float*)d_out, nblocks);
}